// Round 3
// baseline (185.290 us; speedup 1.0000x reference)
//
#include <hip/hip_runtime.h>
#include <hip/hip_bf16.h>
#include <math.h>

#define B_DIM 8
#define C_DIM 32
#define N_DIM 4096
#define NKQ 4                  // K quarters -> 32 waves/CU
#define KSL (N_DIM / NKQ)      // 1024 k per kq-group
#define NCH (KSL / 32)         // 32 chunks

typedef short bf16x8 __attribute__((ext_vector_type(8)));   // 8 bf16 = 4 VGPRs
typedef float f32x4 __attribute__((ext_vector_type(4)));
typedef unsigned int uint4v __attribute__((ext_vector_type(4)));

__device__ __forceinline__ ushort f2bf_rne(float f) {
  unsigned u = __float_as_uint(f);
  u += 0x7FFF + ((u >> 16) & 1);
  return (ushort)(u >> 16);
}

// Fused prep: one pass over x produces both E[b,n] = exp(mean_c x) and the
// tiled bf16 feabT[((b*128 + n/32)*32 + c)*32 + n%32].  (One dispatch fewer,
// x read once instead of twice.)
__global__ __launch_bounds__(256) void prep_fused(const float* __restrict__ x,
                                                  float* __restrict__ E,
                                                  ushort* __restrict__ feabT) {
  int idx = blockIdx.x * 256 + threadIdx.x;   // 0 .. B*N-1
  int b = idx >> 12;
  int n = idx & (N_DIM - 1);
  const float* p = x + (size_t)b * C_DIM * N_DIM + n;
  ushort* q = feabT + ((size_t)(b * (N_DIM / 32) + (n >> 5)) * C_DIM) * 32 + (n & 31);
  float s = 0.f;
#pragma unroll
  for (int c = 0; c < C_DIM; ++c) {
    float v = p[(size_t)c * N_DIM];
    s += v;
    q[c * 32] = f2bf_rne(v);
  }
  E[idx] = __builtin_amdgcn_exp2f(s * (1.44269504f / C_DIM));
}

// Max-occupancy fused GCN kernel.
//   grid = 1024 blocks = 256 colgrps x 4 batch-groups; block = 512 thr =
//   8 waves = 2 batches x 4 K-quarters  ->  4 blocks/CU, 32 waves/CU.
//   The 4 blocks on a CU are independent barrier groups: one group's
//   end-of-chunk drain overlaps another group's compute (the r1 experiment
//   showed the single-group drain was the stall; this multiplies groups
//   instead of removing the drain).
//   Chunk body = the proven r0 two-__syncthreads pipeline (depth-2 adj
//   register staging), keeping r1's verified VALU cuts: transposed stride-36
//   adj tile read as 2x ds_read_b128, pairwise rcp, x2 folded into epilogue.
//   kq partial sums reduce in-block through LDS (no part buffer).
//   Same-XCD L2 reuse: blocks bid, bid+256, +512, +768 share a colgrp's adj
//   slice and land on the same XCD (256 % 8 == 0).
__global__ __launch_bounds__(512, 8) void gcn_fused(
    const ushort* __restrict__ feabT, const float* __restrict__ adj,
    const float* __restrict__ E, const float* __restrict__ para,
    float* __restrict__ out) {
  __shared__ __align__(16) float abuf[NKQ][16 * 36];   // 9.2 KB, [col][k] stride 36
  __shared__ float red[2][NKQ - 1][544];               // 13 KB, stride 17

  const int tid = threadIdx.x;
  const int lane = tid & 63;
  const int w = tid >> 6;          // 0..7
  const int bl = w & 1;            // batch within block
  const int kq = w >> 1;           // 0..3 K-quarter
  const int quad = lane >> 4;
  const int l15 = lane & 15;
  const int bid = blockIdx.x;
  const int colgrp = bid & 255;
  const int bg = bid >> 8;         // 0..3 batch-group
  const int b = bg * 2 + bl;
  const int col = colgrp * 16 + l15;
  const int ksbase = kq * KSL;

  // staging: each kq-group's 128 threads cover its 32x16 adj tile, 4 elems
  // each (rows srow, srow+8, srow+16, srow+24).
  const int tg = tid & 127;
  const int srow = tg >> 4;        // 0..7
  const int scol = tg & 15;
  const float* agp = adj + (size_t)(ksbase + srow) * N_DIM + colgrp * 16 + scol;
  const int swaddr = scol * 36 + srow;   // transposed [col][k]

  const float* Eb = E + (size_t)b * N_DIM;
  const float Em = Eb[col];
  const float* ekb = Eb + ksbase + quad * 8;
  const ushort* fb = feabT + ((size_t)(b * (N_DIM / 32) + (ksbase >> 5))) * (C_DIM * 32);

  f32x4 acc0 = {0.f, 0.f, 0.f, 0.f};   // channels 0-15
  f32x4 acc1 = {0.f, 0.f, 0.f, 0.f};   // channels 16-31

  // depth-2 adj register staging pipeline (r0 structure)
  float a_nxt[4], a_nx2[4];
#pragma unroll
  for (int r = 0; r < 4; ++r) {
    a_nxt[r] = agp[(size_t)(8 * r) * N_DIM];          // tile 0
    a_nx2[r] = agp[(size_t)(32 + 8 * r) * N_DIM];     // tile 1
  }
#pragma unroll
  for (int r = 0; r < 4; ++r) abuf[kq][swaddr + 8 * r] = a_nxt[r];
#pragma unroll
  for (int r = 0; r < 4; ++r) a_nxt[r] = a_nx2[r];
  __syncthreads();

  for (int ch = 0; ch < NCH; ++ch) {
    // issue tile ch+2's staging loads now (~2 chunks of distance to use)
    if (ch + 2 < NCH) {
#pragma unroll
      for (int r = 0; r < 4; ++r)
        a_nx2[r] = agp[(size_t)((ch + 2) * 32 + 8 * r) * N_DIM];
    }

    // fea fragments + E k-values for this wave's batch
    const ushort* tile = fb + (size_t)ch * (C_DIM * 32);
    const bf16x8 fa0 = *(const bf16x8*)(tile + l15 * 32 + quad * 8);
    const bf16x8 fa1 = *(const bf16x8*)(tile + (16 + l15) * 32 + quad * 8);
    float ekv[8];
    *(f32x4*)&ekv[0] = *(const f32x4*)(ekb + ch * 32);
    *(f32x4*)&ekv[4] = *(const f32x4*)(ekb + ch * 32 + 4);

    // adj fragment: 2x ds_read_b128 from the transposed tile
    float av[8];
    *(f32x4*)&av[0] = *(const f32x4*)&abuf[kq][l15 * 36 + quad * 8];
    *(f32x4*)&av[4] = *(const f32x4*)&abuf[kq][l15 * 36 + quad * 8 + 4];

    // w = adj * min(Ek,Em) * rcp(Ek+Em); pairwise-shared rcp
    uint4v wfu;
#pragma unroll
    for (int p = 0; p < 4; ++p) {
      const float e0 = ekv[2 * p];
      const float e1 = ekv[2 * p + 1];
      const float t0 = fminf(e0, Em);
      const float t1 = fminf(e1, Em);
      const float s0 = e0 + Em;
      const float s1 = e1 + Em;
      const float r = __builtin_amdgcn_rcpf(s0 * s1);
      const float w0 = av[2 * p] * t0 * (r * s1);
      const float w1 = av[2 * p + 1] * t1 * (r * s0);
      // truncating bf16x2 pack: bytes [w0.b2, w0.b3, w1.b2, w1.b3]
      wfu[p] = __builtin_amdgcn_perm(__float_as_uint(w1), __float_as_uint(w0),
                                     0x07060302u);
    }
    const bf16x8 wf = __builtin_bit_cast(bf16x8, wfu);

    acc0 = __builtin_amdgcn_mfma_f32_16x16x32_bf16(fa0, wf, acc0, 0, 0, 0);
    acc1 = __builtin_amdgcn_mfma_f32_16x16x32_bf16(fa1, wf, acc1, 0, 0, 0);

    __syncthreads();   // group done reading tile ch
    if (ch + 1 < NCH) {
#pragma unroll
      for (int r = 0; r < 4; ++r) abuf[kq][swaddr + 8 * r] = a_nxt[r];
#pragma unroll
      for (int r = 0; r < 4; ++r) a_nxt[r] = a_nx2[r];
    }
    __syncthreads();   // staged writes visible
  }

  // in-block kq-reduce + epilogue (D layout: col=l15, row=quad*4+r)
  if (kq > 0) {
#pragma unroll
    for (int r = 0; r < 4; ++r) {
      red[bl][kq - 1][(quad * 4 + r) * 17 + l15] = acc0[r];
      red[bl][kq - 1][(16 + quad * 4 + r) * 17 + l15] = acc1[r];
    }
  }
  __syncthreads();
  if (kq == 0) {
#pragma unroll
    for (int r = 0; r < 4; ++r) {
      const int c0 = quad * 4 + r;
      const int c1 = c0 + 16;
      float s0 = acc0[r] + red[bl][0][c0 * 17 + l15] + red[bl][1][c0 * 17 + l15] +
                 red[bl][2][c0 * 17 + l15];
      float s1 = acc1[r] + red[bl][0][c1 * 17 + l15] + red[bl][1][c1 * 17 + l15] +
                 red[bl][2][c1 * 17 + l15];
      s0 *= 2.0f * para[(size_t)c0 * N_DIM + col];   // x2: weight scale folded here
      s1 *= 2.0f * para[(size_t)c1 * N_DIM + col];
      out[((size_t)(b * C_DIM + c0)) * N_DIM + col] = fmaxf(s0, 0.f);
      out[((size_t)(b * C_DIM + c1)) * N_DIM + col] = fmaxf(s1, 0.f);
    }
  }
}

extern "C" void kernel_launch(void* const* d_in, const int* in_sizes, int n_in,
                              void* d_out, int out_size, void* d_ws, size_t ws_size,
                              hipStream_t stream) {
  const float* x = (const float*)d_in[0];     // [8,32,64,64]
  const float* para = (const float*)d_in[1];  // [1,32,64,64]
  const float* adj = (const float*)d_in[2];   // [4096,4096]
  float* out = (float*)d_out;

  // ws: E (128 KB) | feabT (2 MB) -- total 2.25 MB
  float* E = (float*)d_ws;
  ushort* feabT = (ushort*)(E + (size_t)B_DIM * N_DIM);

  prep_fused<<<dim3(B_DIM * N_DIM / 256), dim3(256), 0, stream>>>(x, E, feabT);
  gcn_fused<<<dim3(256 * 4), dim3(512), 0, stream>>>(feabT, adj, E, para, out);
}

// Round 7
// 165.772 us; speedup vs baseline: 1.1177x; 1.1177x over previous
//
#include <hip/hip_runtime.h>
#include <hip/hip_bf16.h>
#include <math.h>

#define B_DIM 8
#define C_DIM 32
#define N_DIM 4096
#define KSL 2048           // k per kh-group
#define NCH (KSL / 32)     // 64 chunks

typedef short bf16x8 __attribute__((ext_vector_type(8)));   // 8 bf16 = 4 VGPRs
typedef float f32x4 __attribute__((ext_vector_type(4)));
typedef unsigned int uint4v __attribute__((ext_vector_type(4)));

__device__ __forceinline__ ushort f2bf_rne(float f) {
  unsigned u = __float_as_uint(f);
  u += 0x7FFF + ((u >> 16) & 1);
  return (ushort)(u >> 16);
}

// Fused prep (verified r3): one pass over x -> E[b,n] = exp(mean_c x) and
// tiled bf16 feabT[((b*128 + n/32)*32 + c)*32 + n%32].
__global__ __launch_bounds__(256) void prep_fused(const float* __restrict__ x,
                                                  float* __restrict__ E,
                                                  ushort* __restrict__ feabT) {
  int idx = blockIdx.x * 256 + threadIdx.x;   // 0 .. B*N-1
  int b = idx >> 12;
  int n = idx & (N_DIM - 1);
  const float* p = x + (size_t)b * C_DIM * N_DIM + n;
  ushort* q = feabT + ((size_t)(b * (N_DIM / 32) + (n >> 5)) * C_DIM) * 32 + (n & 31);
  float s = 0.f;
#pragma unroll
  for (int c = 0; c < C_DIM; ++c) {
    float v = p[(size_t)c * N_DIM];
    s += v;
    q[c * 32] = f2bf_rne(v);
  }
  E[idx] = __builtin_amdgcn_exp2f(s * (1.44269504f / C_DIM));
}

// Barrier-free fused GCN kernel.
//   Same block structure as the 62us r0 kernel (256 blocks x 1024 thr =
//   2 kh-groups x 8 batches), but adj is NOT staged through LDS: each wave
//   loads its own 32x16 adj fragment directly (8 x dword per chunk,
//   64B-coalesced per quad).  The 8 waves of a kh-group request the same 32
//   cache lines within ~a chunk of each other -> L2 dedupes intra-block
//   (unlike r3's cross-block sharing, which measured 4x HBM traffic).
//   Result: the main loop has ZERO barriers / ZERO LDS / no inter-wave
//   coupling -- the per-chunk vmcnt(0)-drain stall (the r0/r1 bottleneck)
//   is structurally gone.  Depth-2 register prefetch for adj (A/B parity,
//   no register copies -- the r1 bug), depth-1 A/B for fea/E (L2-resident).
//   Epilogue: kh=1 stashes partials in LDS (stride 17, conflict-free), one
//   barrier, kh=0 combines + para*relu + stores.
__global__ __launch_bounds__(1024, 4) void gcn_fused(
    const ushort* __restrict__ feabT, const float* __restrict__ adj,
    const float* __restrict__ E, const float* __restrict__ para,
    float* __restrict__ out) {
  __shared__ float red[B_DIM][544];   // 17.4 KB, stride 17

  const int tid = threadIdx.x;
  const int lane = tid & 63;
  const int w = tid >> 6;           // 0..15
  const int b = w & 7;              // batch
  const int kh = w >> 3;            // 0..1 = K-half
  const int quad = lane >> 4;
  const int l15 = lane & 15;
  const int colgrp = blockIdx.x;    // 0..255
  const int col = colgrp * 16 + l15;
  const int ksbase = kh * KSL;

  // per-lane adj pointer: row = ksbase + quad*8 (+j +32*ch), column = col
  const float* ap = adj + (size_t)(ksbase + quad * 8) * N_DIM + col;

  const float* Eb = E + (size_t)b * N_DIM;
  const float Em = Eb[col];
  const float* ekb = Eb + ksbase + quad * 8;
  const ushort* fb = feabT + ((size_t)(b * (N_DIM / 32) + (ksbase >> 5))) * (C_DIM * 32);

  f32x4 acc0 = {0.f, 0.f, 0.f, 0.f};   // channels 0-15
  f32x4 acc1 = {0.f, 0.f, 0.f, 0.f};   // channels 16-31

  // ---- prologue prefetch: adj chunks 0 (A) and 1 (B); fea/E chunk 0 (A)
  float aA[8], aB[8], eA[8], eB[8];
#pragma unroll
  for (int j = 0; j < 8; ++j) aA[j] = ap[(size_t)j * N_DIM];
#pragma unroll
  for (int j = 0; j < 8; ++j) aB[j] = ap[(size_t)(32 + j) * N_DIM];
  bf16x8 f0A = *(const bf16x8*)(fb + l15 * 32 + quad * 8);
  bf16x8 f1A = *(const bf16x8*)(fb + (16 + l15) * 32 + quad * 8);
  *(f32x4*)&eA[0] = *(const f32x4*)(ekb);
  *(f32x4*)&eA[4] = *(const f32x4*)(ekb + 4);
  bf16x8 f0B, f1B;

  auto body = [&](const int ch, float(&aC)[8], const bf16x8 fc0, const bf16x8 fc1,
                  const float(&eC)[8], bf16x8& fn0, bf16x8& fn1, float(&eN)[8]) {
    // fea/E prefetch for chunk ch+1 (L2-resident, 1-chunk distance)
    if (ch + 1 < NCH) {
      const ushort* tn = fb + (size_t)(ch + 1) * (C_DIM * 32);
      fn0 = *(const bf16x8*)(tn + l15 * 32 + quad * 8);
      fn1 = *(const bf16x8*)(tn + (16 + l15) * 32 + quad * 8);
      *(f32x4*)&eN[0] = *(const f32x4*)(ekb + (ch + 1) * 32);
      *(f32x4*)&eN[4] = *(const f32x4*)(ekb + (ch + 1) * 32 + 4);
    }

    // w = adj * min(Ek,Em) * rcp(Ek+Em); pairwise-shared rcp.
    // Consumes aC -> its registers are then refilled for chunk ch+2 below.
    uint4v wfu;
#pragma unroll
    for (int p = 0; p < 4; ++p) {
      const float e0 = eC[2 * p];
      const float e1 = eC[2 * p + 1];
      const float t0 = fminf(e0, Em);
      const float t1 = fminf(e1, Em);
      const float s0 = e0 + Em;
      const float s1 = e1 + Em;
      const float r = __builtin_amdgcn_rcpf(s0 * s1);
      const float w0 = aC[2 * p] * t0 * (r * s1);
      const float w1 = aC[2 * p + 1] * t1 * (r * s0);
      // truncating bf16x2 pack: bytes [w0.b2, w0.b3, w1.b2, w1.b3]
      wfu[p] = __builtin_amdgcn_perm(__float_as_uint(w1), __float_as_uint(w0),
                                     0x07060302u);
    }

    // adj prefetch for chunk ch+2 into the just-freed aC registers
    // (~1.7 chunks of latency distance + 4 waves/SIMD TLP on top)
    if (ch + 2 < NCH) {
#pragma unroll
      for (int j = 0; j < 8; ++j)
        aC[j] = ap[(size_t)((ch + 2) * 32 + j) * N_DIM];
    }

    const bf16x8 wf = __builtin_bit_cast(bf16x8, wfu);
    acc0 = __builtin_amdgcn_mfma_f32_16x16x32_bf16(fc0, wf, acc0, 0, 0, 0);
    acc1 = __builtin_amdgcn_mfma_f32_16x16x32_bf16(fc1, wf, acc1, 0, 0, 0);
  };

  for (int cb = 0; cb < NCH; cb += 2) {
    body(cb, aA, f0A, f1A, eA, f0B, f1B, eB);
    body(cb + 1, aB, f0B, f1B, eB, f0A, f1A, eA);
  }

  // fused kh-reduce + epilogue (D layout: col=l15, row=quad*4+r)
  if (kh == 1) {
#pragma unroll
    for (int r = 0; r < 4; ++r) {
      red[b][(quad * 4 + r) * 17 + l15] = acc0[r];
      red[b][(16 + quad * 4 + r) * 17 + l15] = acc1[r];
    }
  }
  __syncthreads();
  if (kh == 0) {
#pragma unroll
    for (int r = 0; r < 4; ++r) {
      const int c0 = quad * 4 + r;
      const int c1 = c0 + 16;
      float s0 = acc0[r] + red[b][c0 * 17 + l15];
      float s1 = acc1[r] + red[b][c1 * 17 + l15];
      s0 *= 2.0f * para[(size_t)c0 * N_DIM + col];   // x2: weight scale folded here
      s1 *= 2.0f * para[(size_t)c1 * N_DIM + col];
      out[((size_t)(b * C_DIM + c0)) * N_DIM + col] = fmaxf(s0, 0.f);
      out[((size_t)(b * C_DIM + c1)) * N_DIM + col] = fmaxf(s1, 0.f);
    }
  }
}

extern "C" void kernel_launch(void* const* d_in, const int* in_sizes, int n_in,
                              void* d_out, int out_size, void* d_ws, size_t ws_size,
                              hipStream_t stream) {
  const float* x = (const float*)d_in[0];     // [8,32,64,64]
  const float* para = (const float*)d_in[1];  // [1,32,64,64]
  const float* adj = (const float*)d_in[2];   // [4096,4096]
  float* out = (float*)d_out;

  // ws: E (128 KB) | feabT (2 MB) -- total 2.25 MB
  float* E = (float*)d_ws;
  ushort* feabT = (ushort*)(E + (size_t)B_DIM * N_DIM);

  prep_fused<<<dim3(B_DIM * N_DIM / 256), dim3(256), 0, stream>>>(x, E, feabT);
  gcn_fused<<<dim3(N_DIM / 16), dim3(1024), 0, stream>>>(feabT, adj, E, para, out);
}

// Round 8
// 155.635 us; speedup vs baseline: 1.1905x; 1.0651x over previous
//
#include <hip/hip_runtime.h>
#include <hip/hip_bf16.h>
#include <math.h>

#define B_DIM 8
#define C_DIM 32
#define N_DIM 4096
#define KSL 2048           // k per kh-group
#define NCH (KSL / 32)     // 64 chunks

typedef short bf16x8 __attribute__((ext_vector_type(8)));   // 8 bf16 = 4 VGPRs
typedef float f32x4 __attribute__((ext_vector_type(4)));
typedef unsigned int uint4v __attribute__((ext_vector_type(4)));

__device__ __forceinline__ ushort f2bf_rne(float f) {
  unsigned u = __float_as_uint(f);
  u += 0x7FFF + ((u >> 16) & 1);
  return (ushort)(u >> 16);
}

// Fused prep (verified): one pass over x -> E[b,n] = exp(mean_c x) and
// tiled bf16 feabT[((b*128 + n/32)*32 + c)*32 + n%32].
__global__ __launch_bounds__(256) void prep_fused(const float* __restrict__ x,
                                                  float* __restrict__ E,
                                                  ushort* __restrict__ feabT) {
  int idx = blockIdx.x * 256 + threadIdx.x;   // 0 .. B*N-1
  int b = idx >> 12;
  int n = idx & (N_DIM - 1);
  const float* p = x + (size_t)b * C_DIM * N_DIM + n;
  ushort* q = feabT + ((size_t)(b * (N_DIM / 32) + (n >> 5)) * C_DIM) * 32 + (n & 31);
  float s = 0.f;
#pragma unroll
  for (int c = 0; c < C_DIM; ++c) {
    float v = p[(size_t)c * N_DIM];
    s += v;
    q[c * 32] = f2bf_rne(v);
  }
  E[idx] = __builtin_amdgcn_exp2f(s * (1.44269504f / C_DIM));
}

// Fused GCN kernel: LDS-staged adj (minimal VMEM: 1 staging dword + 4 fea/E
// loads per wave per chunk), double-buffered tiles, ONE lgkm-only barrier
// per chunk (global loads never drained in-loop), and a 4-slot rotating
// register staging pipeline with ZERO register copies: tile t is loaded into
// slot t&3 in phase t-4, ds_written in phase t-1, ds_read in phase t.  The
// in-flight register is untouched between load-issue and ds_write, so the
// compiler emits a counted vmcnt(~15) (3 chunks of distance, never stalls)
// -- this avoids r0's vmcnt(0) barrier drain, r1's copy-hoisted wait, and
// r7's 8x VMEM request flood (the three measured ~2300-3500 cyc/chunk
// failure modes).
__global__ __launch_bounds__(1024, 4) void gcn_fused(
    const ushort* __restrict__ feabT, const float* __restrict__ adj,
    const float* __restrict__ E, const float* __restrict__ para,
    float* __restrict__ out) {
  __shared__ __align__(16) float abuf[2][2][16 * 36];  // kh x parity x tile, 9.2 KB
  __shared__ float red[B_DIM][544];                    // stride 17, 17.4 KB

  const int tid = threadIdx.x;
  const int lane = tid & 63;
  const int w = tid >> 6;           // 0..15
  const int b = w & 7;              // batch
  const int kh = w >> 3;            // 0..1 = K-half
  const int quad = lane >> 4;
  const int l15 = lane & 15;
  const int colgrp = blockIdx.x;    // 0..255
  const int col = colgrp * 16 + l15;
  const int ksbase = kh * KSL;

  // staging: each kh-group's 512 threads cover its 32x16 tile, 1 elem each;
  // write transposed [col][k], stride 36 (verified r1 layout).
  const int tg = tid & 511;
  const float* agp = adj + (size_t)(ksbase + (tg >> 4)) * N_DIM + colgrp * 16 + (tg & 15);
  const int swaddr = (tg & 15) * 36 + (tg >> 4);

  const float* Eb = E + (size_t)b * N_DIM;
  const float Em = Eb[col];
  const float* ekb = Eb + ksbase + quad * 8;
  const ushort* fb = feabT + ((size_t)(b * (N_DIM / 32) + (ksbase >> 5))) * (C_DIM * 32);

  f32x4 acc0 = {0.f, 0.f, 0.f, 0.f};   // channels 0-15
  f32x4 acc1 = {0.f, 0.f, 0.f, 0.f};   // channels 16-31

  // ---- prologue: tiles 0..3 in flight; tile 0 -> LDS[0]; fea/E chunk 0 -> X
  float a0 = agp[0];
  float a1 = agp[(size_t)32 * N_DIM];
  float a2 = agp[(size_t)64 * N_DIM];
  float a3 = agp[(size_t)96 * N_DIM];
  bf16x8 fX0 = *(const bf16x8*)(fb + l15 * 32 + quad * 8);
  bf16x8 fX1 = *(const bf16x8*)(fb + (16 + l15) * 32 + quad * 8);
  float eX[8], eY[8];
  *(f32x4*)&eX[0] = *(const f32x4*)(ekb);
  *(f32x4*)&eX[4] = *(const f32x4*)(ekb + 4);
  bf16x8 fY0, fY1;
  abuf[kh][0][swaddr] = a0;   // compiler waits vmcnt for a0 only
  asm volatile("s_waitcnt lgkmcnt(0)\n\ts_barrier" ::: "memory");

  auto phase = [&](const int ch, float& aw /*slot (ch+1)&3: tile ch+1, to stage*/,
                   float& al /*slot ch&3: dead, receives tile ch+4*/,
                   const bf16x8 fc0, const bf16x8 fc1, const float(&eC)[8],
                   bf16x8& fn0, bf16x8& fn1, float(&eN)[8]) {
    const int pb = ch & 1;
    // 1. issue staging load for tile ch+4 (3-phase distance to its ds_write)
    if (ch + 4 < NCH) al = agp[(size_t)((ch + 4) * 32) * N_DIM];
    // 2. fea/E register prefetch for chunk ch+1 (L2-resident)
    if (ch + 1 < NCH) {
      const ushort* tn = fb + (size_t)(ch + 1) * (C_DIM * 32);
      fn0 = *(const bf16x8*)(tn + l15 * 32 + quad * 8);
      fn1 = *(const bf16x8*)(tn + (16 + l15) * 32 + quad * 8);
      *(f32x4*)&eN[0] = *(const f32x4*)(ekb + (ch + 1) * 32);
      *(f32x4*)&eN[4] = *(const f32x4*)(ekb + (ch + 1) * 32 + 4);
    }
    // 3. adj fragment for this chunk: 2x ds_read_b128, bank-balanced
    float av[8];
    *(f32x4*)&av[0] = *(const f32x4*)&abuf[kh][pb][l15 * 36 + quad * 8];
    *(f32x4*)&av[4] = *(const f32x4*)&abuf[kh][pb][l15 * 36 + quad * 8 + 4];
    // 4. stage tile ch+1 into the other buffer (register loaded 3 phases ago;
    //    the vmcnt wait here is counted, never 0)
    if (ch + 1 < NCH) abuf[kh][pb ^ 1][swaddr] = aw;

    // 5. w = adj * min(Ek,Em) * rcp(Ek+Em); pairwise-shared rcp
    uint4v wfu;
#pragma unroll
    for (int p = 0; p < 4; ++p) {
      const float e0 = eC[2 * p];
      const float e1 = eC[2 * p + 1];
      const float t0 = fminf(e0, Em);
      const float t1 = fminf(e1, Em);
      const float s0 = e0 + Em;
      const float s1 = e1 + Em;
      const float r = __builtin_amdgcn_rcpf(s0 * s1);
      const float w0 = av[2 * p] * t0 * (r * s1);
      const float w1 = av[2 * p + 1] * t1 * (r * s0);
      // truncating bf16x2 pack: bytes [w0.b2, w0.b3, w1.b2, w1.b3]
      wfu[p] = __builtin_amdgcn_perm(__float_as_uint(w1), __float_as_uint(w0),
                                     0x07060302u);
    }
    const bf16x8 wf = __builtin_bit_cast(bf16x8, wfu);
    acc0 = __builtin_amdgcn_mfma_f32_16x16x32_bf16(fc0, wf, acc0, 0, 0, 0);
    acc1 = __builtin_amdgcn_mfma_f32_16x16x32_bf16(fc1, wf, acc1, 0, 0, 0);

    // 6. LDS-only wait + barrier: my reads retired (WAR-safe for next write),
    //    my staged write visible; global loads remain in flight.
    asm volatile("s_waitcnt lgkmcnt(0)\n\ts_barrier" ::: "memory");
  };

  for (int cb = 0; cb < NCH; cb += 4) {
    phase(cb + 0, a1, a0, fX0, fX1, eX, fY0, fY1, eY);
    phase(cb + 1, a2, a1, fY0, fY1, eY, fX0, fX1, eX);
    phase(cb + 2, a3, a2, fX0, fX1, eX, fY0, fY1, eY);
    phase(cb + 3, a0, a3, fY0, fY1, eY, fX0, fX1, eX);
  }

  // fused kh-reduce + epilogue (D layout: col=l15, row=quad*4+r)
  if (kh == 1) {
#pragma unroll
    for (int r = 0; r < 4; ++r) {
      red[b][(quad * 4 + r) * 17 + l15] = acc0[r];
      red[b][(16 + quad * 4 + r) * 17 + l15] = acc1[r];
    }
  }
  __syncthreads();
  if (kh == 0) {
#pragma unroll
    for (int r = 0; r < 4; ++r) {
      const int c0 = quad * 4 + r;
      const int c1 = c0 + 16;
      float s0 = acc0[r] + red[b][c0 * 17 + l15];
      float s1 = acc1[r] + red[b][c1 * 17 + l15];
      s0 *= 2.0f * para[(size_t)c0 * N_DIM + col];   // x2: weight scale folded here
      s1 *= 2.0f * para[(size_t)c1 * N_DIM + col];
      out[((size_t)(b * C_DIM + c0)) * N_DIM + col] = fmaxf(s0, 0.f);
      out[((size_t)(b * C_DIM + c1)) * N_DIM + col] = fmaxf(s1, 0.f);
    }
  }
}

extern "C" void kernel_launch(void* const* d_in, const int* in_sizes, int n_in,
                              void* d_out, int out_size, void* d_ws, size_t ws_size,
                              hipStream_t stream) {
  const float* x = (const float*)d_in[0];     // [8,32,64,64]
  const float* para = (const float*)d_in[1];  // [1,32,64,64]
  const float* adj = (const float*)d_in[2];   // [4096,4096]
  float* out = (float*)d_out;

  // ws: E (128 KB) | feabT (2 MB) -- total 2.25 MB
  float* E = (float*)d_ws;
  ushort* feabT = (ushort*)(E + (size_t)B_DIM * N_DIM);

  prep_fused<<<dim3(B_DIM * N_DIM / 256), dim3(256), 0, stream>>>(x, E, feabT);
  gcn_fused<<<dim3(N_DIM / 16), dim3(1024), 0, stream>>>(feabT, adj, E, para, out);
}

// Round 11
// 147.092 us; speedup vs baseline: 1.2597x; 1.0581x over previous
//
#include <hip/hip_runtime.h>
#include <hip/hip_bf16.h>
#include <math.h>

#define B_DIM 8
#define C_DIM 32
#define N_DIM 4096
#define KSL 2048           // k per kh-group
#define NCH (KSL / 32)     // 64 chunks
#define NSUP (NCH / 4)     // 16 supertiles (128 k-rows each)
#define ASTR 132           // LDS word-stride of transposed supertile [col][k]

typedef short bf16x8 __attribute__((ext_vector_type(8)));   // 8 bf16 = 4 VGPRs
typedef float f32x4 __attribute__((ext_vector_type(4)));
typedef unsigned int uint4v __attribute__((ext_vector_type(4)));

__device__ __forceinline__ ushort f2bf_rne(float f) {
  unsigned u = __float_as_uint(f);
  u += 0x7FFF + ((u >> 16) & 1);
  return (ushort)(u >> 16);
}

// Fused prep (verified): one pass over x -> E[b,n] = exp(mean_c x) and
// tiled bf16 feabT[((b*128 + n/32)*32 + c)*32 + n%32].
__global__ __launch_bounds__(256) void prep_fused(const float* __restrict__ x,
                                                  float* __restrict__ E,
                                                  ushort* __restrict__ feabT) {
  int idx = blockIdx.x * 256 + threadIdx.x;   // 0 .. B*N-1
  int b = idx >> 12;
  int n = idx & (N_DIM - 1);
  const float* p = x + (size_t)b * C_DIM * N_DIM + n;
  ushort* q = feabT + ((size_t)(b * (N_DIM / 32) + (n >> 5)) * C_DIM) * 32 + (n & 31);
  float s = 0.f;
#pragma unroll
  for (int c = 0; c < C_DIM; ++c) {
    float v = p[(size_t)c * N_DIM];
    s += v;
    q[c * 32] = f2bf_rne(v);
  }
  E[idx] = __builtin_amdgcn_exp2f(s * (1.44269504f / C_DIM));
}

// Supertile fused GCN kernel.
//   r0/r1/r7/r8 all measured 2300-3100 cyc/chunk vs ~600 cyc of issue: the
//   gap is latency exposed at per-chunk barrier drains (128 of them).  Fix:
//   barrier once per 4 chunks.  Each kh-group stages a 128k x 16col adj
//   SUPERTILE (1 global_load_dwordx4 + 4 ds_write_b32 per thread), double-
//   buffered, ONE plain __syncthreads per supertile.  Every load reaching a
//   barrier drain is >= 4 chunks old -> vmcnt(0) drain free by construction
//   (no asm barriers -- r1/r8's "memory"-clobber asm forced a hidden full
//   drain and regressed).  Within a supertile the 4 chunks are barrier-free:
//   compiler hoists all fea/E loads (16-deep MLP), waves drift (TLP).
//   Register staging uses strict A/B parity, zero copies (r1 lesson).
//   Weight math / layouts / epilogue identical to the verified kernels.
__global__ __launch_bounds__(1024, 4) void gcn_fused(
    const ushort* __restrict__ feabT, const float* __restrict__ adj,
    const float* __restrict__ E, const float* __restrict__ para,
    float* __restrict__ out) {
  __shared__ __align__(16) float abuf[2][2][16 * ASTR];  // kh x parity, 33.8 KB
  __shared__ float red[B_DIM][544];                      // stride 17, 17.4 KB

  const int tid = threadIdx.x;
  const int lane = tid & 63;
  const int w = tid >> 6;           // 0..15
  const int b = w & 7;              // batch
  const int kh = w >> 3;            // 0..1 = K-half
  const int quad = lane >> 4;
  const int l15 = lane & 15;
  const int colgrp = blockIdx.x;    // 0..255
  const int col = colgrp * 16 + l15;
  const int ksbase = kh * KSL;

  // supertile staging: 512 threads cover 128 rows x 16 cols, one f32x4 each
  const int tg = tid & 511;
  const int srow = tg >> 2;         // 0..127
  const int scq = tg & 3;           // col quad: cols scq*4 .. scq*4+3
  const float* agp = adj + (size_t)(ksbase + srow) * N_DIM + colgrp * 16 + scq * 4;

  const float* Eb = E + (size_t)b * N_DIM;
  const float Em = Eb[col];
  const float* ekb = Eb + ksbase + quad * 8;
  const ushort* fb = feabT + ((size_t)(b * (N_DIM / 32) + (ksbase >> 5))) * (C_DIM * 32);

  f32x4 acc0 = {0.f, 0.f, 0.f, 0.f};   // channels 0-15
  f32x4 acc1 = {0.f, 0.f, 0.f, 0.f};   // channels 16-31

  // ---- prologue: ST0 -> RA -> LDS buf0; ST1 -> RB (stays in flight)
  f32x4 RA = *(const f32x4*)(agp);
  f32x4 RB = *(const f32x4*)(agp + (size_t)128 * N_DIM);
#pragma unroll
  for (int i = 0; i < 4; ++i) abuf[kh][0][(scq * 4 + i) * ASTR + srow] = RA[i];
  __syncthreads();   // drains RB too (once, prologue only)

  // 4 barrier-free chunks from supertile s in LDS buffer p
  auto compute4 = [&](const int s, const int p) {
    const float* ab = &abuf[kh][p][0];
#pragma unroll
    for (int ch = 0; ch < 4; ++ch) {
      const int gch = s * 4 + ch;
      const ushort* tile = fb + (size_t)gch * (C_DIM * 32);
      const bf16x8 fa0 = *(const bf16x8*)(tile + l15 * 32 + quad * 8);
      const bf16x8 fa1 = *(const bf16x8*)(tile + (16 + l15) * 32 + quad * 8);
      float ekv[8];
      *(f32x4*)&ekv[0] = *(const f32x4*)(ekb + gch * 32);
      *(f32x4*)&ekv[4] = *(const f32x4*)(ekb + gch * 32 + 4);
      float av[8];
      *(f32x4*)&av[0] = *(const f32x4*)(ab + l15 * ASTR + ch * 32 + quad * 8);
      *(f32x4*)&av[4] = *(const f32x4*)(ab + l15 * ASTR + ch * 32 + quad * 8 + 4);

      // w = adj * min(Ek,Em) * rcp(Ek+Em); pairwise-shared rcp
      uint4v wfu;
#pragma unroll
      for (int pq = 0; pq < 4; ++pq) {
        const float e0 = ekv[2 * pq];
        const float e1 = ekv[2 * pq + 1];
        const float t0 = fminf(e0, Em);
        const float t1 = fminf(e1, Em);
        const float s0 = e0 + Em;
        const float s1 = e1 + Em;
        const float r = __builtin_amdgcn_rcpf(s0 * s1);
        const float w0 = av[2 * pq] * t0 * (r * s1);
        const float w1 = av[2 * pq + 1] * t1 * (r * s0);
        // truncating bf16x2 pack: bytes [w0.b2, w0.b3, w1.b2, w1.b3]
        wfu[pq] = __builtin_amdgcn_perm(__float_as_uint(w1), __float_as_uint(w0),
                                        0x07060302u);
      }
      const bf16x8 wf = __builtin_bit_cast(bf16x8, wfu);
      acc0 = __builtin_amdgcn_mfma_f32_16x16x32_bf16(fa0, wf, acc0, 0, 0, 0);
      acc1 = __builtin_amdgcn_mfma_f32_16x16x32_bf16(fa1, wf, acc1, 0, 0, 0);
    }
  };

  for (int s = 0; s < NSUP; s += 2) {
    // even supertile s (buf0): issue ST(s+2)->RA; stage ST(s+1)=RB -> buf1
    if (s + 2 < NSUP) RA = *(const f32x4*)(agp + (size_t)(s + 2) * 128 * N_DIM);
#pragma unroll
    for (int i = 0; i < 4; ++i) abuf[kh][1][(scq * 4 + i) * ASTR + srow] = RB[i];
    compute4(s, 0);
    __syncthreads();   // drain is of >=4-chunk-old loads: free

    // odd supertile s+1 (buf1): issue ST(s+3)->RB; stage ST(s+2)=RA -> buf0
    if (s + 3 < NSUP) RB = *(const f32x4*)(agp + (size_t)(s + 3) * 128 * N_DIM);
    if (s + 2 < NSUP) {
#pragma unroll
      for (int i = 0; i < 4; ++i) abuf[kh][0][(scq * 4 + i) * ASTR + srow] = RA[i];
    }
    compute4(s + 1, 1);
    __syncthreads();
  }

  // fused kh-reduce + epilogue (D layout: col=l15, row=quad*4+r)
  if (kh == 1) {
#pragma unroll
    for (int r = 0; r < 4; ++r) {
      red[b][(quad * 4 + r) * 17 + l15] = acc0[r];
      red[b][(16 + quad * 4 + r) * 17 + l15] = acc1[r];
    }
  }
  __syncthreads();
  if (kh == 0) {
#pragma unroll
    for (int r = 0; r < 4; ++r) {
      const int c0 = quad * 4 + r;
      const int c1 = c0 + 16;
      float s0 = acc0[r] + red[b][c0 * 17 + l15];
      float s1 = acc1[r] + red[b][c1 * 17 + l15];
      s0 *= 2.0f * para[(size_t)c0 * N_DIM + col];   // x2: weight scale folded here
      s1 *= 2.0f * para[(size_t)c1 * N_DIM + col];
      out[((size_t)(b * C_DIM + c0)) * N_DIM + col] = fmaxf(s0, 0.f);
      out[((size_t)(b * C_DIM + c1)) * N_DIM + col] = fmaxf(s1, 0.f);
    }
  }
}

extern "C" void kernel_launch(void* const* d_in, const int* in_sizes, int n_in,
                              void* d_out, int out_size, void* d_ws, size_t ws_size,
                              hipStream_t stream) {
  const float* x = (const float*)d_in[0];     // [8,32,64,64]
  const float* para = (const float*)d_in[1];  // [1,32,64,64]
  const float* adj = (const float*)d_in[2];   // [4096,4096]
  float* out = (float*)d_out;

  // ws: E (128 KB) | feabT (2 MB) -- total 2.25 MB
  float* E = (float*)d_ws;
  ushort* feabT = (ushort*)(E + (size_t)B_DIM * N_DIM);

  prep_fused<<<dim3(B_DIM * N_DIM / 256), dim3(256), 0, stream>>>(x, E, feabT);
  gcn_fused<<<dim3(N_DIM / 16), dim3(1024), 0, stream>>>(feabT, adj, E, para, out);
}